// Round 6
// baseline (331.633 us; speedup 1.0000x reference)
//
#include <hip/hip_runtime.h>
#include <stdint.h>
#include <stddef.h>

// Problem constants
#define IN_F   4096
#define OUT_F  14336
#define TOK    32

// Tiling
#define OTILE  64                 // output features per block (16 per wave)
#define ISPLIT 16                 // grid.y split over the reduction dim
#define IBLK   (IN_F / ISPLIT)    // 256 i per block
#define KBPB   (IBLK / 32)        // 8 K-blocks (MFMA K=32) per block

typedef __attribute__((ext_vector_type(8))) short bf16x8;
typedef __attribute__((ext_vector_type(4))) float f32x4;

// prep: write xs = x*scales as bf16 in MFMA A-operand fragment order:
//   element (t,i): kb=i>>5, mt=t>>4, lane=((i>>3)&3)*16 + (t&15), j=i&7
//   int4 slot index = (kb*2+mt)*64 + lane   (j packed inside the int4)
// Each thread handles 8 consecutive i of one t -> exactly one int4 slot.
// Also zeroes d_out (qgemm accumulates with atomicAdd).
__global__ __launch_bounds__(256) void prep_kernel(
    const float* __restrict__ x, const float* __restrict__ scales,
    int4* __restrict__ xfrag, float* __restrict__ out)
{
    const int f = blockIdx.x * 256 + threadIdx.x;   // grid 512 -> 0..131071
    if (f < (TOK * IN_F / 8)) {                     // 16384 frag slots
        const int t  = f >> 9;                      // 0..31
        const int i8 = f & 511;                     // i = 8*i8 .. 8*i8+7
        const int kb = i8 >> 2;                     // i>>5
        const int kg = i8 & 3;                      // (i>>3)&3
        const float4* xp = (const float4*)(x + (size_t)t * IN_F + i8 * 8);
        const float4* sp = (const float4*)(scales + i8 * 8);
        float4 x0 = xp[0], x1 = xp[1];
        float4 s0 = sp[0], s1 = sp[1];
        float v[8] = { x0.x*s0.x, x0.y*s0.y, x0.z*s0.z, x0.w*s0.w,
                       x1.x*s1.x, x1.y*s1.y, x1.z*s1.z, x1.w*s1.w };
        uint32_t h[8];
#pragma unroll
        for (int j = 0; j < 8; ++j) {               // fp32 -> bf16 RNE
            uint32_t b = __float_as_uint(v[j]);
            b += 0x7fffu + ((b >> 16) & 1u);
            h[j] = b >> 16;
        }
        int4 d;
        d.x = (int)(h[0] | (h[1] << 16));
        d.y = (int)(h[2] | (h[3] << 16));
        d.z = (int)(h[4] | (h[5] << 16));
        d.w = (int)(h[6] | (h[7] << 16));
        xfrag[((kb * 2 + (t >> 4)) * 64) + kg * 16 + (t & 15)] = d;
    }
    if (f < (OUT_F * TOK / 4)) {                    // zero 458752 floats
        ((float4*)out)[f] = make_float4(0.f, 0.f, 0.f, 0.f);
    }
}

// Main kernel: NO LDS, NO __syncthreads. Each wave is fully independent:
// wave owns 16 o-rows x all 32 tokens x IBLK i. B-fragments load straight
// from global into VGPRs (lane lx,quad reads 32 B of row ob+lx at k=quad*8);
// per instruction = 16 x 128 B fully-consumed segments. Full K-unroll lets
// the compiler keep many loads in flight with fine-grained vmcnt — no
// barrier ever forces vmcnt(0). A (x, bf16) lives in 64 VGPRs loaded once.
// int->bf16 cvt is EXACT (|w|<=127 fits bf16's 8-bit mantissa).
__global__ __launch_bounds__(256, 4) void qgemm_kernel(
    const int* __restrict__ wgt, const int4* __restrict__ xfrag,
    float* __restrict__ out)
{
    const int lane = threadIdx.x & 63;
    const int wv   = threadIdx.x >> 6;              // 0..3
    const int lx   = lane & 15;                     // B col = o offset
    const int quad = lane >> 4;                     // B k-group
    const int ob   = blockIdx.x * OTILE + wv * 16;  // my wave's o-base
    const int ib0  = blockIdx.y * IBLK;

    // Load my A fragments once: 8 kb x 2 mt int4 = 64 VGPRs, fully coalesced.
    int4 a[KBPB][2];
#pragma unroll
    for (int kb = 0; kb < KBPB; ++kb)
#pragma unroll
        for (int mt = 0; mt < 2; ++mt)
            a[kb][mt] = xfrag[((blockIdx.y * KBPB + kb) * 2 + mt) * 64 + lane];

    f32x4 acc[2] = { {0.f,0.f,0.f,0.f}, {0.f,0.f,0.f,0.f} };

    // my B row pointer: row ob+lx, k base ib0 + quad*8
    const int* wp = wgt + (size_t)(ob + lx) * IN_F + ib0 + quad * 8;

#pragma unroll
    for (int kb = 0; kb < KBPB; ++kb) {
        // 8 consecutive int32 at k = ib0 + kb*32 + quad*8 + (0..7)
        const int4 w0 = *(const int4*)(wp + kb * 32);
        const int4 w1 = *(const int4*)(wp + kb * 32 + 4);
        bf16x8 b;
        b[0] = (short)(__float_as_uint((float)w0.x) >> 16);
        b[1] = (short)(__float_as_uint((float)w0.y) >> 16);
        b[2] = (short)(__float_as_uint((float)w0.z) >> 16);
        b[3] = (short)(__float_as_uint((float)w0.w) >> 16);
        b[4] = (short)(__float_as_uint((float)w1.x) >> 16);
        b[5] = (short)(__float_as_uint((float)w1.y) >> 16);
        b[6] = (short)(__float_as_uint((float)w1.z) >> 16);
        b[7] = (short)(__float_as_uint((float)w1.w) >> 16);
        bf16x8 a0, a1;
        __builtin_memcpy(&a0, &a[kb][0], 16);
        __builtin_memcpy(&a1, &a[kb][1], 16);
        acc[0] = __builtin_amdgcn_mfma_f32_16x16x32_bf16(a0, b, acc[0], 0, 0, 0);
        acc[1] = __builtin_amdgcn_mfma_f32_16x16x32_bf16(a1, b, acc[1], 0, 0, 0);
    }

    // C/D layout: D[row=quad*4+reg][col=lx]; t = mt*16 + quad*4 + reg.
    // ISPLIT partials -> fp32 atomics (out zeroed by prep).
#pragma unroll
    for (int mt = 0; mt < 2; ++mt)
#pragma unroll
        for (int reg = 0; reg < 4; ++reg) {
            const int t = mt * 16 + quad * 4 + reg;
            atomicAdd(&out[(size_t)t * OUT_F + ob + lx], acc[mt][reg]);
        }
}

extern "C" void kernel_launch(void* const* d_in, const int* in_sizes, int n_in,
                              void* d_out, int out_size, void* d_ws, size_t ws_size,
                              hipStream_t stream)
{
    const float* x      = (const float*)d_in[0];   // [32, 4096] fp32
    const int*   wgt    = (const int*)d_in[1];     // [14336, 4096] int32 (int8 vals)
    const float* scales = (const float*)d_in[2];   // [4096] fp32
    float* out = (float*)d_out;                    // [32, 14336] fp32
    int4*  xfrag = (int4*)d_ws;                    // 256 KB scratch (A-frags)

    prep_kernel<<<dim3((TOK * IN_F) / 256), 256, 0, stream>>>(x, scales, xfrag, out);

    dim3 grid(OUT_F / OTILE, ISPLIT);              // 224 x 16 = 3584 blocks
    qgemm_kernel<<<grid, 256, 0, stream>>>(wgt, xfrag, out);
}